// Round 13
// baseline (462.538 us; speedup 1.0000x reference)
//
#include <hip/hip_runtime.h>
#include <hip/hip_bf16.h>
#include <stdint.h>

// Problem constants
#define B_   16
#define C_   512
#define N_   1024   // H*W = 32*32
#define C3   1536   // 3*C
#define NPAD 1156   // (32+2)*(32+2) padded image positions

using bf16x8 = __attribute__((ext_vector_type(8))) __bf16;
using f32x4  = __attribute__((ext_vector_type(4))) float;
typedef unsigned short ushort_t;

__device__ __forceinline__ ushort_t f2bf(float f) {
    union { float f; uint32_t u; } v; v.f = f;
    uint32_t r = v.u + 0x7FFFu + ((v.u >> 16) & 1u);   // RNE
    return (ushort_t)(r >> 16);
}

typedef __attribute__((address_space(3))) void lds_void_t;
typedef const __attribute__((address_space(1))) void g_void_t;
__device__ __forceinline__ void gload16(const void* g, void* l) {
    __builtin_amdgcn_global_load_lds((g_void_t*)g, (lds_void_t*)l, 16, 0, 0);
}

// ---------------------------------------------------------------------------
// Small prep kernels
// ---------------------------------------------------------------------------

// wf [C][3C] fp32 -> bf16, plus zero page + concat bias
__global__ void castwf_kernel(const float* __restrict__ wf,
                              ushort_t* __restrict__ Wfb,
                              ushort_t* __restrict__ zp,
                              const float* __restrict__ b1,
                              const float* __restrict__ b2,
                              const float* __restrict__ b3,
                              float* __restrict__ b_all) {
    int idx = blockIdx.x * 256 + threadIdx.x;
    if (idx < 512) zp[idx] = 0;
    if (idx < 1536) b_all[idx] = (idx < 512) ? b1[idx] : (idx < 1024) ? b2[idx - 512] : b3[idx - 1024];
    Wfb[idx] = f2bf(wf[idx]);
}

// all three w [co][ci][3][3] fp32 -> Wall[t][c*512+co][ci] bf16 (t = kh*3+kw)
__global__ void castw3_kernel(const float* __restrict__ w1,
                              const float* __restrict__ w2,
                              const float* __restrict__ w3,
                              ushort_t* __restrict__ Wall) {
    int idx = blockIdx.x * 256 + threadIdx.x;          // c*9*C*C + t*C*C + co*C + ci
    int c = idx / (9 * C_ * C_);
    int r = idx - c * (9 * C_ * C_);
    int t = r / (C_ * C_);
    int rem = r - t * (C_ * C_);                       // co*C + ci
    const float* w = (c == 0) ? w1 : (c == 1) ? w2 : w3;
    Wall[(size_t)t * (C3 * C_) + (size_t)c * 512 * C_ + rem] = f2bf(w[(size_t)rem * 9 + t]);
}

// x [b][c][n] fp32 -> Xb bf16, transposed into cat[b][n][c], and into padded
// catP[b][(h+1)*34+(w+1)][c] (ring rows pre-zeroed by hipMemsetAsync).
__global__ void castx_kernel(const float* __restrict__ x,
                             ushort_t* __restrict__ Xb,
                             ushort_t* __restrict__ cat,
                             ushort_t* __restrict__ catP) {
    __shared__ ushort_t t[32][33];
    int n0 = blockIdx.x * 32, c0 = blockIdx.y * 32, b = blockIdx.z;
    int tx = threadIdx.x & 31, ty = threadIdx.x >> 5;  // 32 x 8
    const float* xb = x + ((size_t)b * C_ + c0) * N_ + n0;
#pragma unroll
    for (int q = 0; q < 4; ++q) {
        int c = ty + q * 8;
        ushort_t h = f2bf(xb[(size_t)c * N_ + tx]);
        Xb[((size_t)b * C_ + c0 + c) * N_ + n0 + tx] = h;
        t[c][tx] = h;
    }
    __syncthreads();
#pragma unroll
    for (int q = 0; q < 4; ++q) {
        int n = ty + q * 8;
        ushort_t v = t[tx][n];
        cat[((size_t)b * N_ + n0 + n) * C3 + c0 + tx] = v;
        int prow = (n0 >> 5) * 34 + n + 35;            // (h+1)*34 + (w+1), n0 mult of 32
        catP[((size_t)b * NPAD + prow) * C_ + c0 + tx] = v;
    }
}

// Y[:, 1024:1536] ([b,n][co] view) -> Db[b][co][n]
__global__ void transp_kernel(const ushort_t* __restrict__ Y,
                              ushort_t* __restrict__ Db) {
    __shared__ ushort_t t[32][33];
    int n0 = blockIdx.x * 32, c0 = blockIdx.y * 32, b = blockIdx.z;
    int tx = threadIdx.x & 31, ty = threadIdx.x >> 5;  // 32 x 8
#pragma unroll
    for (int q = 0; q < 4; ++q) {
        int n = ty + q * 8;
        t[n][tx] = Y[((size_t)b * N_ + n0 + n) * C3 + 1024 + c0 + tx];
    }
    __syncthreads();
#pragma unroll
    for (int q = 0; q < 4; ++q) {
        int c = ty + q * 8;
        Db[((size_t)b * C_ + c0 + c) * N_ + n0 + tx] = t[tx][c];
    }
}

// Row softmax of M [N][N] fp32, write bf16 P in place (row-local)
__global__ void softmax_kernel(float* __restrict__ Mb) {
    int n = blockIdx.x, b = blockIdx.y;
    float* row = Mb + ((size_t)b * N_ + n) * N_;
    int tid = threadIdx.x;
    float4 v = ((const float4*)row)[tid];
    float m = fmaxf(fmaxf(v.x, v.y), fmaxf(v.z, v.w));
#pragma unroll
    for (int off = 1; off < 64; off <<= 1) m = fmaxf(m, __shfl_xor(m, off));
    __shared__ float sm[4], ss[4];
    int wid = tid >> 6, lane = tid & 63;
    if (lane == 0) sm[wid] = m;
    __syncthreads();
    m = fmaxf(fmaxf(sm[0], sm[1]), fmaxf(sm[2], sm[3]));
    float e0 = __expf(v.x - m), e1 = __expf(v.y - m);
    float e2 = __expf(v.z - m), e3 = __expf(v.w - m);
    float s = e0 + e1 + e2 + e3;
#pragma unroll
    for (int off = 1; off < 64; off <<= 1) s += __shfl_xor(s, off);
    if (lane == 0) ss[wid] = s;
    __syncthreads();
    s = ss[0] + ss[1] + ss[2] + ss[3];
    float r = 1.0f / s;
    ushort4 o;
    o.x = f2bf(e0 * r); o.y = f2bf(e1 * r); o.z = f2bf(e2 * r); o.w = f2bf(e3 * r);
    ((ushort4*)row)[tid] = o;   // all reads happened before the barriers above
}

// Per-row max / 1/sumexp of Sraw [C][C]
__global__ void rowstats_kernel(const float* __restrict__ S,
                                float* __restrict__ mxv, float* __restrict__ rzv) {
    int c = blockIdx.x, b = blockIdx.y;
    const float* row = S + ((size_t)b * C_ + c) * C_;
    int tid = threadIdx.x;
    float2 v = ((const float2*)row)[tid];
    float m = fmaxf(v.x, v.y);
#pragma unroll
    for (int off = 1; off < 64; off <<= 1) m = fmaxf(m, __shfl_xor(m, off));
    __shared__ float sm[4], ss[4];
    int wid = tid >> 6, lane = tid & 63;
    if (lane == 0) sm[wid] = m;
    __syncthreads();
    m = fmaxf(fmaxf(sm[0], sm[1]), fmaxf(sm[2], sm[3]));
    float e = __expf(v.x - m) + __expf(v.y - m);
#pragma unroll
    for (int off = 1; off < 64; off <<= 1) e += __shfl_xor(e, off);
    if (lane == 0) ss[wid] = e;
    __syncthreads();
    if (tid == 0) {
        e = ss[0] + ss[1] + ss[2] + ss[3];
        mxv[(size_t)b * C_ + c] = m;
        rzv[(size_t)b * C_ + c] = 1.0f / e;
    }
}

// Sst[b][c][d] = softmax(S,axis=-1)^T [c][d] = exp(Sraw[c][d]-mx[d])*rz[d]
// (vectorized x4; C=512 divisible by 4 so d..d+3 stay in-row)
__global__ void sst_kernel(const float* __restrict__ S,
                           const float* __restrict__ mxv, const float* __restrict__ rzv,
                           ushort_t* __restrict__ Sst) {
    int idx = blockIdx.x * 256 + threadIdx.x;          // over B*C*C/4
    int e = idx * 4;
    int d = e & (C_ - 1);
    int b = e >> 18;
    float4 v = ((const float4*)S)[idx];
    const float* mb = mxv + ((size_t)b << 9);
    const float* rb = rzv + ((size_t)b << 9);
    ushort4 o;
    o.x = f2bf(__expf(v.x - mb[d]) * rb[d]);
    o.y = f2bf(__expf(v.y - mb[d + 1]) * rb[d + 1]);
    o.z = f2bf(__expf(v.z - mb[d + 2]) * rb[d + 2]);
    o.w = f2bf(__expf(v.w - mb[d + 3]) * rb[d + 3]);
    ((ushort4*)Sst)[idx] = o;
}

// ---------------------------------------------------------------------------
// 128x128 2-phase gemm_bt (proven baseline) — used only for Sraw now.
// ---------------------------------------------------------------------------
#define BM 128
#define BN 128
#define BKk 64

template <int XMODE, int OUTF32, int BIASMODE, int SCALE, int SWZ>
__global__ __launch_bounds__(256)
void gemm_bt_kernel(const ushort_t* __restrict__ Ab, int lda, long long strideA, long long tapA,
                    const ushort_t* __restrict__ Bb, int ldb, long long strideB, long long tapB,
                    void* __restrict__ Cb, int ldc, long long strideC,
                    int K, int ntaps,
                    const float* __restrict__ bias,
                    const float* __restrict__ scaleptr,
                    const ushort_t* __restrict__ zpage) {
    __shared__ short As[BM * BKk];
    __shared__ short Bs[BN * BKk];
    int tid = threadIdx.x;
    int wid = tid >> 6, lane = tid & 63;
    int wr = wid >> 1, wc = wid & 1;
    int j0 = blockIdx.x * BN, i0 = blockIdx.y * BM, b = blockIdx.z;
    const ushort_t* Abase = Ab + (size_t)b * strideA;
    const ushort_t* Bbase = Bb + (size_t)b * strideB;

    f32x4 acc[4][4] = {};

    int rs = wid * 32 + (lane >> 3);
    int kb = (lane & 7) * 8;

    for (int tap = 0; tap < ntaps; ++tap) {
        const ushort_t* At_ = Abase + (size_t)tap * tapA;
        const ushort_t* Bt_ = Bbase + (size_t)tap * tapB;
        const ushort_t* aq[4];
        const ushort_t* bq[4];
#pragma unroll
        for (int q = 0; q < 4; ++q)
            aq[q] = At_ + (size_t)(i0 + rs + q * 8) * lda + kb;
#pragma unroll
        for (int q = 0; q < 4; ++q)
            bq[q] = Bt_ + (size_t)(j0 + rs + q * 8) * ldb + kb;

        for (int kk = 0; kk < K; kk += BKk) {
            __syncthreads();
#pragma unroll
            for (int q = 0; q < 4; ++q) {
                gload16(aq[q], &As[(wid * 32 + q * 8) * BKk]);
                aq[q] += BKk;
                gload16(bq[q], &Bs[(wid * 32 + q * 8) * BKk]);
                bq[q] += BKk;
            }
            __syncthreads();
#pragma unroll
            for (int kc = 0; kc < BKk; kc += 32) {
                bf16x8 af[4], bfr[4];
#pragma unroll
                for (int m = 0; m < 4; ++m)
                    af[m] = *(const bf16x8*)&As[(wr * 64 + m * 16 + (lane & 15)) * BKk + kc + (lane >> 4) * 8];
#pragma unroll
                for (int nb = 0; nb < 4; ++nb)
                    bfr[nb] = *(const bf16x8*)&Bs[(wc * 64 + nb * 16 + (lane & 15)) * BKk + kc + (lane >> 4) * 8];
#pragma unroll
                for (int m = 0; m < 4; ++m)
#pragma unroll
                    for (int nb = 0; nb < 4; ++nb)
                        acc[m][nb] = __builtin_amdgcn_mfma_f32_16x16x32_bf16(af[m], bfr[nb], acc[m][nb], 0, 0, 0);
            }
        }
    }

    float scale = SCALE ? *scaleptr : 1.0f;
#pragma unroll
    for (int m = 0; m < 4; ++m) {
#pragma unroll
        for (int nb = 0; nb < 4; ++nb) {
            int i = i0 + wr * 64 + m * 16 + (lane >> 4) * 4;
            int j = j0 + wc * 64 + nb * 16 + (lane & 15);
#pragma unroll
            for (int r = 0; r < 4; ++r) {
                float v = acc[m][nb][r];
                if (BIASMODE == 1) v += bias[i + r];
                if (BIASMODE == 2) v += bias[j];
                if (SCALE) v *= scale;
                if (OUTF32)
                    ((float*)Cb)[(size_t)b * strideC + (size_t)(i + r) * ldc + j] = v;
                else
                    ((ushort_t*)Cb)[(size_t)b * strideC + (size_t)(i + r) * ldc + j] = f2bf(v);
            }
        }
    }
}

// ---------------------------------------------------------------------------
// Ring-3 pipelined 256x128 GEMM (round-10 proven engine, 8 waves x 64x64).
// Used for M / PV / chan / out. UNCHANGED.
// ---------------------------------------------------------------------------
#define R3BM 256
#define R3BN 128
#define R3BK 64

template <int XMODE, int OUTF32, int BIASMODE, int SCALE>
__global__ __launch_bounds__(512, 2)
void gemm_r3_kernel(const ushort_t* __restrict__ Ab, int lda, long long strideA, long long tapA,
                    const ushort_t* __restrict__ Bb, int ldb, long long strideB, long long tapB,
                    void* __restrict__ Cb, int ldc, long long strideC,
                    int K, int ntaps,
                    const float* __restrict__ bias,
                    const float* __restrict__ scaleptr,
                    const ushort_t* __restrict__ zpage) {
    __shared__ short As[3][R3BM * R3BK];   // 3 x 32 KiB
    __shared__ short Bs[3][R3BN * R3BK];   // 3 x 16 KiB
    int tid = threadIdx.x;
    int wid = tid >> 6, lane = tid & 63;
    int wr = wid >> 1, wc = wid & 1;       // 4 M-waves x 2 N-waves
    int j0 = blockIdx.x * R3BN, i0 = blockIdx.y * R3BM, b = blockIdx.z;
    int kpt = K >> 6;                      // K-tiles per tap
    int nt = ntaps * kpt;

    f32x4 acc[4][4] = {};

    int sr = tid >> 3;                     // staging row 0..63 (+s*64)
    int klds = (tid & 7) * 8;              // LDS k-slot base (elems)
    int sbase = wid * 512;                 // staging LDS dest base (elems)

    // ---- hoisted fragment LDS offsets (tile-invariant) ----
    int aoff[4][2], boff[4][2];
#pragma unroll
    for (int m = 0; m < 4; ++m) {
        int row = wr * 64 + m * 16 + (lane & 15);
        int sw = (row & 7) << 3;
#pragma unroll
        for (int h = 0; h < 2; ++h)
            aoff[m][h] = row * R3BK + ((h * 32 + (lane >> 4) * 8) ^ sw);
    }
#pragma unroll
    for (int nb = 0; nb < 4; ++nb) {
        int row = wc * 64 + nb * 16 + (lane & 15);
        int sw = (row & 7) << 3;
#pragma unroll
        for (int h = 0; h < 2; ++h)
            boff[nb][h] = row * R3BK + ((h * 32 + (lane >> 4) * 8) ^ sw);
    }

    // ---- persistent per-thread staging base pointers ----
    const ushort_t* pa[4];
    const ushort_t* pb[2];
#pragma unroll
    for (int s = 0; s < 4; ++s) {
        int r = sr + s * 64;
        int ks = klds ^ ((r & 7) << 3);            // T2 pre-swizzled source col
        if (XMODE == 1) {
            int li = (i0 & (N_ - 1)) + r;          // row within image
            int pr = (li >> 5) * 34 + (li & 31) + 35;   // padded position, tap 0,0
            pa[s] = Ab + ((size_t)(i0 >> 10) * NPAD + pr) * lda + ks;
        } else {
            pa[s] = Ab + (size_t)b * strideA + (size_t)(i0 + r) * lda + ks;
        }
    }
#pragma unroll
    for (int s = 0; s < 2; ++s) {
        int r = sr + s * 64;
        int ks = klds ^ ((r & 7) << 3);
        pb[s] = Bb + (size_t)b * strideB + (size_t)(j0 + r) * ldb + ks;
    }

    int s_tap = 0, s_kk = 0;               // staging-side (tap,kk), tap-minor
    auto STAGE = [&](int slot) {
        long long uA, uB;
        if (XMODE == 1) {
            int dh = s_tap / 3 - 1, dw = s_tap - (s_tap / 3) * 3 - 1;
            uA = (long long)(dh * 34 + dw) * lda + s_kk * R3BK;
        } else {
            uA = (long long)s_tap * tapA + (long long)s_kk * R3BK;
        }
        uB = (long long)s_tap * tapB + (long long)s_kk * R3BK;
#pragma unroll
        for (int s = 0; s < 4; ++s)
            gload16(pa[s] + uA, &As[slot][sbase + s * 4096]);
#pragma unroll
        for (int s = 0; s < 2; ++s)
            gload16(pb[s] + uB, &Bs[slot][sbase + s * 4096]);
        if (++s_tap == ntaps) { s_tap = 0; ++s_kk; }
    };

    // prologue: stage tiles 0,1
    STAGE(0);
    STAGE(1);

    for (int t = 0; t < nt; ++t) {
        int slot = t - (t / 3) * 3;        // t % 3
        if (t + 1 < nt) asm volatile("s_waitcnt vmcnt(6)" ::: "memory");
        else            asm volatile("s_waitcnt vmcnt(0)" ::: "memory");
        __builtin_amdgcn_s_barrier();
        __builtin_amdgcn_sched_barrier(0);

        const short* Aslot = &As[slot][0];
        const short* Bslot = &Bs[slot][0];
        bf16x8 af[4][2], bfr[4][2];
#pragma unroll
        for (int h = 0; h < 2; ++h) {      // h0 reads first (lgkmcnt(8) split)
#pragma unroll
            for (int m = 0; m < 4; ++m)
                af[m][h] = *(const bf16x8*)&Aslot[aoff[m][h]];
#pragma unroll
            for (int nb = 0; nb < 4; ++nb)
                bfr[nb][h] = *(const bf16x8*)&Bslot[boff[nb][h]];
        }

        if (t + 2 < nt) STAGE((t + 2) - ((t + 2) / 3) * 3);

        asm volatile("s_waitcnt lgkmcnt(8)" ::: "memory");
        __builtin_amdgcn_sched_barrier(0);
        __builtin_amdgcn_s_setprio(1);
#pragma unroll
        for (int m = 0; m < 4; ++m)
#pragma unroll
            for (int nb = 0; nb < 4; ++nb)
                acc[m][nb] = __builtin_amdgcn_mfma_f32_16x16x32_bf16(af[m][0], bfr[nb][0], acc[m][nb], 0, 0, 0);
        asm volatile("s_waitcnt lgkmcnt(0)" ::: "memory");
        __builtin_amdgcn_sched_barrier(0);
#pragma unroll
        for (int m = 0; m < 4; ++m)
#pragma unroll
            for (int nb = 0; nb < 4; ++nb)
                acc[m][nb] = __builtin_amdgcn_mfma_f32_16x16x32_bf16(af[m][1], bfr[nb][1], acc[m][nb], 0, 0, 0);
        __builtin_amdgcn_s_setprio(0);
    }

    float scale = SCALE ? *scaleptr : 1.0f;
#pragma unroll
    for (int m = 0; m < 4; ++m) {
#pragma unroll
        for (int nb = 0; nb < 4; ++nb) {
            int i = i0 + wr * 64 + m * 16 + (lane >> 4) * 4;
            int j = j0 + wc * 64 + nb * 16 + (lane & 15);
#pragma unroll
            for (int r = 0; r < 4; ++r) {
                float v = acc[m][nb][r];
                if (BIASMODE == 1) v += bias[i + r];
                if (BIASMODE == 2) v += bias[j];
                if (SCALE) v *= scale;
                if (OUTF32)
                    ((float*)Cb)[(size_t)b * strideC + (size_t)(i + r) * ldc + j] = v;
                else
                    ((ushort_t*)Cb)[(size_t)b * strideC + (size_t)(i + r) * ldc + j] = f2bf(v);
            }
        }
    }
}

// ---------------------------------------------------------------------------
// Ring-3 "fat-wave" 256x128 GEMM: 256 threads = 4 waves (2M x 2N), per-wave
// 128x64 (acc[8][4]). Same sync skeleton/ledger as gemm_r3_kernel, counts
// rescaled: STAGE = 12 issues (A 8 + B 4), steady vmcnt(12), lgkm split 12.
// Rationale (r12 analysis): LDS frag traffic drops 128->96 KB per K-tile
// (each A elem read by 2 N-waves instead of... B by 2 M-waves instead of 4),
// and per-wave MFMA ILP doubles (64 independent MFMAs). LDS 144 KiB -> 1
// block/CU, 1 wave/SIMD; launch_bounds(256,1) allows ~280 VGPR without spill.
// Conv only. Bit-identical output (same per-element accumulation order).
// ---------------------------------------------------------------------------
#define RFBM 256
#define RFBN 128
#define RFBK 64

template <int XMODE, int OUTF32, int BIASMODE, int SCALE>
__global__ __launch_bounds__(256, 1)
void gemm_r3f_kernel(const ushort_t* __restrict__ Ab, int lda, long long strideA, long long tapA,
                     const ushort_t* __restrict__ Bb, int ldb, long long strideB, long long tapB,
                     void* __restrict__ Cb, int ldc, long long strideC,
                     int K, int ntaps,
                     const float* __restrict__ bias,
                     const float* __restrict__ scaleptr) {
    __shared__ short As[3][RFBM * RFBK];   // 3 x 32 KiB
    __shared__ short Bs[3][RFBN * RFBK];   // 3 x 16 KiB
    int tid = threadIdx.x;
    int wid = tid >> 6, lane = tid & 63;
    int wr = wid >> 1, wc = wid & 1;       // 2 M-waves x 2 N-waves, wave tile 128x64
    int j0 = blockIdx.x * RFBN, i0 = blockIdx.y * RFBM, b = blockIdx.z;
    int kpt = K >> 6;
    int nt = ntaps * kpt;

    f32x4 acc[8][4] = {};

    int sr = tid >> 3;                     // staging row 0..31 (+s*32)
    int klds = (tid & 7) * 8;
    int sbase = wid * 512;                 // wave rows wid*8..wid*8+7 per issue

    // ---- hoisted fragment LDS offsets (tile-invariant) ----
    int aoff[8][2], boff[4][2];
#pragma unroll
    for (int m = 0; m < 8; ++m) {
        int row = wr * 128 + m * 16 + (lane & 15);
        int sw = (row & 7) << 3;
#pragma unroll
        for (int h = 0; h < 2; ++h)
            aoff[m][h] = row * RFBK + ((h * 32 + (lane >> 4) * 8) ^ sw);
    }
#pragma unroll
    for (int nb = 0; nb < 4; ++nb) {
        int row = wc * 64 + nb * 16 + (lane & 15);
        int sw = (row & 7) << 3;
#pragma unroll
        for (int h = 0; h < 2; ++h)
            boff[nb][h] = row * RFBK + ((h * 32 + (lane >> 4) * 8) ^ sw);
    }

    // ---- persistent per-thread staging base pointers ----
    const ushort_t* pa[8];
    const ushort_t* pb[4];
#pragma unroll
    for (int s = 0; s < 8; ++s) {
        int r = sr + s * 32;
        int ks = klds ^ ((r & 7) << 3);            // T2 pre-swizzled source col
        if (XMODE == 1) {
            int li = (i0 & (N_ - 1)) + r;          // row within image
            int pr = (li >> 5) * 34 + (li & 31) + 35;   // padded position, tap 0,0
            pa[s] = Ab + ((size_t)(i0 >> 10) * NPAD + pr) * lda + ks;
        } else {
            pa[s] = Ab + (size_t)b * strideA + (size_t)(i0 + r) * lda + ks;
        }
    }
#pragma unroll
    for (int s = 0; s < 4; ++s) {
        int r = sr + s * 32;
        int ks = klds ^ ((r & 7) << 3);
        pb[s] = Bb + (size_t)b * strideB + (size_t)(j0 + r) * ldb + ks;
    }

    int s_tap = 0, s_kk = 0;               // staging-side (tap,kk), tap-minor
    auto STAGE = [&](int slot) {
        long long uA, uB;
        if (XMODE == 1) {
            int dh = s_tap / 3 - 1, dw = s_tap - (s_tap / 3) * 3 - 1;
            uA = (long long)(dh * 34 + dw) * lda + s_kk * RFBK;
        } else {
            uA = (long long)s_tap * tapA + (long long)s_kk * RFBK;
        }
        uB = (long long)s_tap * tapB + (long long)s_kk * RFBK;
#pragma unroll
        for (int s = 0; s < 8; ++s)
            gload16(pa[s] + uA, &As[slot][sbase + s * 2048]);
#pragma unroll
        for (int s = 0; s < 4; ++s)
            gload16(pb[s] + uB, &Bs[slot][sbase + s * 2048]);
        if (++s_tap == ntaps) { s_tap = 0; ++s_kk; }
    };

    // prologue: stage tiles 0,1 (24 loads outstanding)
    STAGE(0);
    STAGE(1);

    for (int t = 0; t < nt; ++t) {
        int slot = t - (t / 3) * 3;        // t % 3
        if (t + 1 < nt) asm volatile("s_waitcnt vmcnt(12)" ::: "memory");
        else            asm volatile("s_waitcnt vmcnt(0)" ::: "memory");
        __builtin_amdgcn_s_barrier();
        __builtin_amdgcn_sched_barrier(0);

        const short* Aslot = &As[slot][0];
        const short* Bslot = &Bs[slot][0];
        bf16x8 af[8][2], bfr[4][2];
#pragma unroll
        for (int h = 0; h < 2; ++h) {      // h0 reads first (lgkmcnt(12) split)
#pragma unroll
            for (int m = 0; m < 8; ++m)
                af[m][h] = *(const bf16x8*)&Aslot[aoff[m][h]];
#pragma unroll
            for (int nb = 0; nb < 4; ++nb)
                bfr[nb][h] = *(const bf16x8*)&Bslot[boff[nb][h]];
        }

        if (t + 2 < nt) STAGE((t + 2) - ((t + 2) / 3) * 3);

        asm volatile("s_waitcnt lgkmcnt(12)" ::: "memory");
        __builtin_amdgcn_sched_barrier(0);
        __builtin_amdgcn_s_setprio(1);
#pragma unroll
        for (int m = 0; m < 8; ++m)
#pragma unroll
            for (int nb = 0; nb < 4; ++nb)
                acc[m][nb] = __builtin_amdgcn_mfma_f32_16x16x32_bf16(af[m][0], bfr[nb][0], acc[m][nb], 0, 0, 0);
        asm volatile("s_waitcnt lgkmcnt(0)" ::: "memory");
        __builtin_amdgcn_sched_barrier(0);
#pragma unroll
        for (int m = 0; m < 8; ++m)
#pragma unroll
            for (int nb = 0; nb < 4; ++nb)
                acc[m][nb] = __builtin_amdgcn_mfma_f32_16x16x32_bf16(af[m][1], bfr[nb][1], acc[m][nb], 0, 0, 0);
        __builtin_amdgcn_s_setprio(0);
    }

    float scale = SCALE ? *scaleptr : 1.0f;
#pragma unroll
    for (int m = 0; m < 8; ++m) {
#pragma unroll
        for (int nb = 0; nb < 4; ++nb) {
            int i = i0 + wr * 128 + m * 16 + (lane >> 4) * 4;
            int j = j0 + wc * 64 + nb * 16 + (lane & 15);
#pragma unroll
            for (int r = 0; r < 4; ++r) {
                float v = acc[m][nb][r];
                if (BIASMODE == 1) v += bias[i + r];
                if (BIASMODE == 2) v += bias[j];
                if (SCALE) v *= scale;
                if (OUTF32)
                    ((float*)Cb)[(size_t)b * strideC + (size_t)(i + r) * ldc + j] = v;
                else
                    ((ushort_t*)Cb)[(size_t)b * strideC + (size_t)(i + r) * ldc + j] = f2bf(v);
            }
        }
    }
}

// ---------------------------------------------------------------------------
// Workspace layout (bytes). Wall+Xb+catP alias the M region (all dead before
// the M GEMM writes it): 14.2 + 16.8 + 18.9 = 49.9 MB < 67.1 MB.
// ---------------------------------------------------------------------------
constexpr size_t OFF_ZP   = 0;
constexpr size_t OFF_BALL = 1024;
constexpr size_t OFF_WFB  = OFF_BALL + 6144;
constexpr size_t OFF_CAT  = OFF_WFB + (size_t)C_ * C3 * 2;
constexpr size_t OFF_Y    = OFF_CAT + (size_t)B_ * N_ * C3 * 2;
constexpr size_t OFF_DB   = OFF_Y + (size_t)B_ * N_ * C3 * 2;
constexpr size_t OFF_SR   = OFF_DB + (size_t)B_ * C_ * N_ * 2;
constexpr size_t OFF_SST  = OFF_SR + (size_t)B_ * C_ * C_ * 4;
constexpr size_t OFF_MX   = OFF_SST + (size_t)B_ * C_ * C_ * 2;
constexpr size_t OFF_RZ   = OFF_MX + (size_t)B_ * C_ * 4;
constexpr size_t OFF_U    = OFF_RZ + (size_t)B_ * C_ * 4;
constexpr size_t WALL_SZ  = (size_t)9 * C3 * C_ * 2;
constexpr size_t XB_SZ    = (size_t)B_ * C_ * N_ * 2;
constexpr size_t CATP_SZ  = (size_t)B_ * NPAD * C_ * 2;
constexpr size_t OFF_WALL = OFF_U;
constexpr size_t OFF_XB   = OFF_U + WALL_SZ;
constexpr size_t OFF_CATP = OFF_XB + XB_SZ;
constexpr size_t OFF_M    = OFF_U;
constexpr size_t EXT_A    = OFF_CATP + CATP_SZ;
constexpr size_t EXT_B    = OFF_M + (size_t)B_ * N_ * N_ * 4;
constexpr size_t WS_NEED  = EXT_A > EXT_B ? EXT_A : EXT_B;

extern "C" void kernel_launch(void* const* d_in, const int* in_sizes, int n_in,
                              void* d_out, int out_size, void* d_ws, size_t ws_size,
                              hipStream_t stream) {
    const float* x   = (const float*)d_in[0];
    const float* w1  = (const float*)d_in[1];
    const float* b1  = (const float*)d_in[2];
    const float* w2  = (const float*)d_in[3];
    const float* b2  = (const float*)d_in[4];
    const float* w3  = (const float*)d_in[5];
    const float* b3  = (const float*)d_in[6];
    const float* alpha = (const float*)d_in[7];
    const float* beta  = (const float*)d_in[8];
    const float* wf  = (const float*)d_in[9];
    const float* bfv = (const float*)d_in[10];
    float* out = (float*)d_out;
    char* ws = (char*)d_ws;
    if (ws_size < WS_NEED) return;

    ushort_t* zp   = (ushort_t*)(ws + OFF_ZP);
    float*    ball = (float*)(ws + OFF_BALL);
    ushort_t* Wfb  = (ushort_t*)(ws + OFF_WFB);
    ushort_t* cat  = (ushort_t*)(ws + OFF_CAT);
    ushort_t* Y    = (ushort_t*)(ws + OFF_Y);
    ushort_t* Db   = (ushort_t*)(ws + OFF_DB);
    float*    Sr   = (float*)(ws + OFF_SR);
    ushort_t* Sst  = (ushort_t*)(ws + OFF_SST);
    float*    mxv  = (float*)(ws + OFF_MX);
    float*    rzv  = (float*)(ws + OFF_RZ);
    ushort_t* Wall = (ushort_t*)(ws + OFF_WALL);
    ushort_t* Xb   = (ushort_t*)(ws + OFF_XB);
    ushort_t* catP = (ushort_t*)(ws + OFF_CATP);
    float*    Mb   = (float*)(ws + OFF_M);

    // zero the catP pad ring (interior overwritten by castx)
    hipMemsetAsync(catP, 0, CATP_SZ, stream);

    castwf_kernel<<<(C_ * C3) / 256, 256, 0, stream>>>(wf, Wfb, zp, b1, b2, b3, ball);
    castw3_kernel<<<(3 * 9 * C_ * C_) / 256, 256, 0, stream>>>(w1, w2, w3, Wall);
    castx_kernel<<<dim3(N_ / 32, C_ / 32, B_), 256, 0, stream>>>(x, Xb, cat, catP);

    // Fused 3-conv, ONE dispatch, fat-wave engine: Y[(b,n)][co_all].
    // 12 x 64 = 768 blocks (1/CU, 3 rounds); catP + kk-major keeps L2-hot.
    gemm_r3f_kernel<1, 0, 2, 0><<<dim3(12, 64, 1), 256, 0, stream>>>(
        catP, C_, 0, 0,
        Wall, C_, 0, (long long)C3 * C_,
        Y, C3, 0,
        C_, 9, ball, nullptr);
    // Db[b][co][n] = transpose of Y[:, 1024:1536]
    transp_kernel<<<dim3(N_ / 32, C_ / 32, B_), 256, 0, stream>>>(Y, Db);
    // Sraw[c][d] = Xb . Xb^T (fp32)  (128x128 2-phase baseline kernel)
    gemm_bt_kernel<0, 1, 0, 0, 0><<<dim3(4, 4, B_), 256, 0, stream>>>(
        Xb, N_, (long long)C_ * N_, 0,
        Xb, N_, (long long)C_ * N_, 0,
        Sr, C_, (long long)C_ * C_,
        N_, 1, nullptr, nullptr, zp);
    rowstats_kernel<<<dim3(C_, B_), 256, 0, stream>>>(Sr, mxv, rzv);
    sst_kernel<<<(B_ * C_ * C_ / 4) / 256, 256, 0, stream>>>(Sr, mxv, rzv, Sst);
    // M[n][m] = At . Bt^T (fp32), At = Y[:, :512], Bt = Y[:, 512:1024]
    gemm_r3_kernel<0, 1, 0, 0><<<dim3(8, 4, B_), 512, 0, stream>>>(
        Y, C3, (long long)N_ * C3, 0,
        Y + 512, C3, (long long)N_ * C3, 0,
        Mb, N_, (long long)N_ * N_,
        C_, 1, nullptr, nullptr, zp);
    // row softmax -> bf16 P in place (row stride 2048 ushorts)
    softmax_kernel<<<dim3(N_, B_), 256, 0, stream>>>(Mb);
    // spat_t[n][c] = alpha * P . Db^T  -> cat cols [512,1024)
    gemm_r3_kernel<0, 0, 0, 1><<<dim3(4, 4, B_), 512, 0, stream>>>(
        (const ushort_t*)Mb, 2048, (long long)N_ * 2048, 0,
        Db, N_, (long long)C_ * N_, 0,
        cat + 512, C3, (long long)N_ * C3,
        N_, 1, nullptr, alpha, zp);
    // chan_t[n][c] = beta * Xt . Sst^T -> cat cols [1024,1536)
    gemm_r3_kernel<0, 0, 0, 1><<<dim3(4, 4, B_), 512, 0, stream>>>(
        cat, C3, (long long)N_ * C3, 0,
        Sst, C_, (long long)C_ * C_, 0,
        cat + 1024, C3, (long long)N_ * C3,
        C_, 1, nullptr, beta, zp);
    // out[co][n] = Wfb . cat^T + bf (fp32)
    gemm_r3_kernel<0, 1, 1, 0><<<dim3(8, 2, B_), 512, 0, stream>>>(
        Wfb, C3, 0, 0,
        cat, C3, (long long)N_ * C3, 0,
        out, N_, (long long)C_ * N_,
        C3, 1, bfv, nullptr, zp);
}

// Round 14
// 432.123 us; speedup vs baseline: 1.0704x; 1.0704x over previous
//
#include <hip/hip_runtime.h>
#include <hip/hip_bf16.h>
#include <stdint.h>

// Problem constants
#define B_   16
#define C_   512
#define N_   1024   // H*W = 32*32
#define C3   1536   // 3*C
#define NPAD 1156   // (32+2)*(32+2) padded image positions

using bf16x8 = __attribute__((ext_vector_type(8))) __bf16;
using f32x4  = __attribute__((ext_vector_type(4))) float;
typedef unsigned short ushort_t;

__device__ __forceinline__ ushort_t f2bf(float f) {
    union { float f; uint32_t u; } v; v.f = f;
    uint32_t r = v.u + 0x7FFFu + ((v.u >> 16) & 1u);   // RNE
    return (ushort_t)(r >> 16);
}

typedef __attribute__((address_space(3))) void lds_void_t;
typedef const __attribute__((address_space(1))) void g_void_t;
__device__ __forceinline__ void gload16(const void* g, void* l) {
    __builtin_amdgcn_global_load_lds((g_void_t*)g, (lds_void_t*)l, 16, 0, 0);
}

// ---------------------------------------------------------------------------
// Small prep kernels
// ---------------------------------------------------------------------------

// wf [C][3C] fp32 -> bf16, plus zero page + concat bias
__global__ void castwf_kernel(const float* __restrict__ wf,
                              ushort_t* __restrict__ Wfb,
                              ushort_t* __restrict__ zp,
                              const float* __restrict__ b1,
                              const float* __restrict__ b2,
                              const float* __restrict__ b3,
                              float* __restrict__ b_all) {
    int idx = blockIdx.x * 256 + threadIdx.x;
    if (idx < 512) zp[idx] = 0;
    if (idx < 1536) b_all[idx] = (idx < 512) ? b1[idx] : (idx < 1024) ? b2[idx - 512] : b3[idx - 1024];
    Wfb[idx] = f2bf(wf[idx]);
}

// all three w [co][ci][3][3] fp32 -> Wall[t][c*512+co][ci] bf16 (t = kh*3+kw)
__global__ void castw3_kernel(const float* __restrict__ w1,
                              const float* __restrict__ w2,
                              const float* __restrict__ w3,
                              ushort_t* __restrict__ Wall) {
    int idx = blockIdx.x * 256 + threadIdx.x;          // c*9*C*C + t*C*C + co*C + ci
    int c = idx / (9 * C_ * C_);
    int r = idx - c * (9 * C_ * C_);
    int t = r / (C_ * C_);
    int rem = r - t * (C_ * C_);                       // co*C + ci
    const float* w = (c == 0) ? w1 : (c == 1) ? w2 : w3;
    Wall[(size_t)t * (C3 * C_) + (size_t)c * 512 * C_ + rem] = f2bf(w[(size_t)rem * 9 + t]);
}

// x [b][c][n] fp32 -> Xb bf16, transposed into cat[b][n][c], and into padded
// catP[b][(h+1)*34+(w+1)][c] (ring rows pre-zeroed by hipMemsetAsync).
__global__ void castx_kernel(const float* __restrict__ x,
                             ushort_t* __restrict__ Xb,
                             ushort_t* __restrict__ cat,
                             ushort_t* __restrict__ catP) {
    __shared__ ushort_t t[32][33];
    int n0 = blockIdx.x * 32, c0 = blockIdx.y * 32, b = blockIdx.z;
    int tx = threadIdx.x & 31, ty = threadIdx.x >> 5;  // 32 x 8
    const float* xb = x + ((size_t)b * C_ + c0) * N_ + n0;
#pragma unroll
    for (int q = 0; q < 4; ++q) {
        int c = ty + q * 8;
        ushort_t h = f2bf(xb[(size_t)c * N_ + tx]);
        Xb[((size_t)b * C_ + c0 + c) * N_ + n0 + tx] = h;
        t[c][tx] = h;
    }
    __syncthreads();
#pragma unroll
    for (int q = 0; q < 4; ++q) {
        int n = ty + q * 8;
        ushort_t v = t[tx][n];
        cat[((size_t)b * N_ + n0 + n) * C3 + c0 + tx] = v;
        int prow = (n0 >> 5) * 34 + n + 35;            // (h+1)*34 + (w+1), n0 mult of 32
        catP[((size_t)b * NPAD + prow) * C_ + c0 + tx] = v;
    }
}

// Y[:, 1024:1536] ([b,n][co] view) -> Db[b][co][n]
__global__ void transp_kernel(const ushort_t* __restrict__ Y,
                              ushort_t* __restrict__ Db) {
    __shared__ ushort_t t[32][33];
    int n0 = blockIdx.x * 32, c0 = blockIdx.y * 32, b = blockIdx.z;
    int tx = threadIdx.x & 31, ty = threadIdx.x >> 5;  // 32 x 8
#pragma unroll
    for (int q = 0; q < 4; ++q) {
        int n = ty + q * 8;
        t[n][tx] = Y[((size_t)b * N_ + n0 + n) * C3 + 1024 + c0 + tx];
    }
    __syncthreads();
#pragma unroll
    for (int q = 0; q < 4; ++q) {
        int c = ty + q * 8;
        Db[((size_t)b * C_ + c0 + c) * N_ + n0 + tx] = t[tx][c];
    }
}

// Row softmax of M [N][N] fp32, write bf16 P in place (row-local)
__global__ void softmax_kernel(float* __restrict__ Mb) {
    int n = blockIdx.x, b = blockIdx.y;
    float* row = Mb + ((size_t)b * N_ + n) * N_;
    int tid = threadIdx.x;
    float4 v = ((const float4*)row)[tid];
    float m = fmaxf(fmaxf(v.x, v.y), fmaxf(v.z, v.w));
#pragma unroll
    for (int off = 1; off < 64; off <<= 1) m = fmaxf(m, __shfl_xor(m, off));
    __shared__ float sm[4], ss[4];
    int wid = tid >> 6, lane = tid & 63;
    if (lane == 0) sm[wid] = m;
    __syncthreads();
    m = fmaxf(fmaxf(sm[0], sm[1]), fmaxf(sm[2], sm[3]));
    float e0 = __expf(v.x - m), e1 = __expf(v.y - m);
    float e2 = __expf(v.z - m), e3 = __expf(v.w - m);
    float s = e0 + e1 + e2 + e3;
#pragma unroll
    for (int off = 1; off < 64; off <<= 1) s += __shfl_xor(s, off);
    if (lane == 0) ss[wid] = s;
    __syncthreads();
    s = ss[0] + ss[1] + ss[2] + ss[3];
    float r = 1.0f / s;
    ushort4 o;
    o.x = f2bf(e0 * r); o.y = f2bf(e1 * r); o.z = f2bf(e2 * r); o.w = f2bf(e3 * r);
    ((ushort4*)row)[tid] = o;   // all reads happened before the barriers above
}

// Per-row max / 1/sumexp of Sraw [C][C]
__global__ void rowstats_kernel(const float* __restrict__ S,
                                float* __restrict__ mxv, float* __restrict__ rzv) {
    int c = blockIdx.x, b = blockIdx.y;
    const float* row = S + ((size_t)b * C_ + c) * C_;
    int tid = threadIdx.x;
    float2 v = ((const float2*)row)[tid];
    float m = fmaxf(v.x, v.y);
#pragma unroll
    for (int off = 1; off < 64; off <<= 1) m = fmaxf(m, __shfl_xor(m, off));
    __shared__ float sm[4], ss[4];
    int wid = tid >> 6, lane = tid & 63;
    if (lane == 0) sm[wid] = m;
    __syncthreads();
    m = fmaxf(fmaxf(sm[0], sm[1]), fmaxf(sm[2], sm[3]));
    float e = __expf(v.x - m) + __expf(v.y - m);
#pragma unroll
    for (int off = 1; off < 64; off <<= 1) e += __shfl_xor(e, off);
    if (lane == 0) ss[wid] = e;
    __syncthreads();
    if (tid == 0) {
        e = ss[0] + ss[1] + ss[2] + ss[3];
        mxv[(size_t)b * C_ + c] = m;
        rzv[(size_t)b * C_ + c] = 1.0f / e;
    }
}

// Sst[b][c][d] = softmax(S,axis=-1)^T [c][d] = exp(Sraw[c][d]-mx[d])*rz[d]
// (vectorized x4; C=512 divisible by 4 so d..d+3 stay in-row)
__global__ void sst_kernel(const float* __restrict__ S,
                           const float* __restrict__ mxv, const float* __restrict__ rzv,
                           ushort_t* __restrict__ Sst) {
    int idx = blockIdx.x * 256 + threadIdx.x;          // over B*C*C/4
    int e = idx * 4;
    int d = e & (C_ - 1);
    int b = e >> 18;
    float4 v = ((const float4*)S)[idx];
    const float* mb = mxv + ((size_t)b << 9);
    const float* rb = rzv + ((size_t)b << 9);
    ushort4 o;
    o.x = f2bf(__expf(v.x - mb[d]) * rb[d]);
    o.y = f2bf(__expf(v.y - mb[d + 1]) * rb[d + 1]);
    o.z = f2bf(__expf(v.z - mb[d + 2]) * rb[d + 2]);
    o.w = f2bf(__expf(v.w - mb[d + 3]) * rb[d + 3]);
    ((ushort4*)Sst)[idx] = o;
}

// ---------------------------------------------------------------------------
// 128x128 2-phase gemm_bt (proven baseline) — used only for Sraw now.
// ---------------------------------------------------------------------------
#define BM 128
#define BN 128
#define BKk 64

template <int XMODE, int OUTF32, int BIASMODE, int SCALE, int SWZ>
__global__ __launch_bounds__(256)
void gemm_bt_kernel(const ushort_t* __restrict__ Ab, int lda, long long strideA, long long tapA,
                    const ushort_t* __restrict__ Bb, int ldb, long long strideB, long long tapB,
                    void* __restrict__ Cb, int ldc, long long strideC,
                    int K, int ntaps,
                    const float* __restrict__ bias,
                    const float* __restrict__ scaleptr,
                    const ushort_t* __restrict__ zpage) {
    __shared__ short As[BM * BKk];
    __shared__ short Bs[BN * BKk];
    int tid = threadIdx.x;
    int wid = tid >> 6, lane = tid & 63;
    int wr = wid >> 1, wc = wid & 1;
    int j0 = blockIdx.x * BN, i0 = blockIdx.y * BM, b = blockIdx.z;
    const ushort_t* Abase = Ab + (size_t)b * strideA;
    const ushort_t* Bbase = Bb + (size_t)b * strideB;

    f32x4 acc[4][4] = {};

    int rs = wid * 32 + (lane >> 3);
    int kb = (lane & 7) * 8;

    for (int tap = 0; tap < ntaps; ++tap) {
        const ushort_t* At_ = Abase + (size_t)tap * tapA;
        const ushort_t* Bt_ = Bbase + (size_t)tap * tapB;
        const ushort_t* aq[4];
        const ushort_t* bq[4];
#pragma unroll
        for (int q = 0; q < 4; ++q)
            aq[q] = At_ + (size_t)(i0 + rs + q * 8) * lda + kb;
#pragma unroll
        for (int q = 0; q < 4; ++q)
            bq[q] = Bt_ + (size_t)(j0 + rs + q * 8) * ldb + kb;

        for (int kk = 0; kk < K; kk += BKk) {
            __syncthreads();
#pragma unroll
            for (int q = 0; q < 4; ++q) {
                gload16(aq[q], &As[(wid * 32 + q * 8) * BKk]);
                aq[q] += BKk;
                gload16(bq[q], &Bs[(wid * 32 + q * 8) * BKk]);
                bq[q] += BKk;
            }
            __syncthreads();
#pragma unroll
            for (int kc = 0; kc < BKk; kc += 32) {
                bf16x8 af[4], bfr[4];
#pragma unroll
                for (int m = 0; m < 4; ++m)
                    af[m] = *(const bf16x8*)&As[(wr * 64 + m * 16 + (lane & 15)) * BKk + kc + (lane >> 4) * 8];
#pragma unroll
                for (int nb = 0; nb < 4; ++nb)
                    bfr[nb] = *(const bf16x8*)&Bs[(wc * 64 + nb * 16 + (lane & 15)) * BKk + kc + (lane >> 4) * 8];
#pragma unroll
                for (int m = 0; m < 4; ++m)
#pragma unroll
                    for (int nb = 0; nb < 4; ++nb)
                        acc[m][nb] = __builtin_amdgcn_mfma_f32_16x16x32_bf16(af[m], bfr[nb], acc[m][nb], 0, 0, 0);
            }
        }
    }

    float scale = SCALE ? *scaleptr : 1.0f;
#pragma unroll
    for (int m = 0; m < 4; ++m) {
#pragma unroll
        for (int nb = 0; nb < 4; ++nb) {
            int i = i0 + wr * 64 + m * 16 + (lane >> 4) * 4;
            int j = j0 + wc * 64 + nb * 16 + (lane & 15);
#pragma unroll
            for (int r = 0; r < 4; ++r) {
                float v = acc[m][nb][r];
                if (BIASMODE == 1) v += bias[i + r];
                if (BIASMODE == 2) v += bias[j];
                if (SCALE) v *= scale;
                if (OUTF32)
                    ((float*)Cb)[(size_t)b * strideC + (size_t)(i + r) * ldc + j] = v;
                else
                    ((ushort_t*)Cb)[(size_t)b * strideC + (size_t)(i + r) * ldc + j] = f2bf(v);
            }
        }
    }
}

// ---------------------------------------------------------------------------
// Ring-3 pipelined 256x128 GEMM (round-10 proven engine, reverted to exactly).
//   vmcnt(6) -> barrier -> 16 ds_read burst -> STAGE(t+2) -> lgkm(8) MFMA h0
//   -> lgkm(0) MFMA h1, setprio around MFMA. Zero bank conflicts (T2).
// Round-11/13 lessons: the up-front 16-read burst + lgkm(8)/lgkm(0) split and
// the 8-wave 64x64 geometry are jointly the local optimum of this one-barrier
// skeleton — finer interleave (r11), smaller BK (r9), fatter waves (r13) all
// regressed. Path beyond is the two-barrier 8-phase schedule (not attempted:
// race risk from prose reconstruction).
// XMODE=1: A = padded catP, tap shift = wave-uniform (dh*34+dw)*lda,
// kk-major/tap-minor enumeration (round-8 proven: FETCH 287->48 MB).
// ---------------------------------------------------------------------------
#define R3BM 256
#define R3BN 128
#define R3BK 64

template <int XMODE, int OUTF32, int BIASMODE, int SCALE>
__global__ __launch_bounds__(512, 2)
void gemm_r3_kernel(const ushort_t* __restrict__ Ab, int lda, long long strideA, long long tapA,
                    const ushort_t* __restrict__ Bb, int ldb, long long strideB, long long tapB,
                    void* __restrict__ Cb, int ldc, long long strideC,
                    int K, int ntaps,
                    const float* __restrict__ bias,
                    const float* __restrict__ scaleptr,
                    const ushort_t* __restrict__ zpage) {
    __shared__ short As[3][R3BM * R3BK];   // 3 x 32 KiB
    __shared__ short Bs[3][R3BN * R3BK];   // 3 x 16 KiB
    int tid = threadIdx.x;
    int wid = tid >> 6, lane = tid & 63;
    int wr = wid >> 1, wc = wid & 1;       // 4 M-waves x 2 N-waves
    int j0 = blockIdx.x * R3BN, i0 = blockIdx.y * R3BM, b = blockIdx.z;
    int kpt = K >> 6;                      // K-tiles per tap
    int nt = ntaps * kpt;

    f32x4 acc[4][4] = {};

    int sr = tid >> 3;                     // staging row 0..63 (+s*64)
    int klds = (tid & 7) * 8;              // LDS k-slot base (elems)
    int sbase = wid * 512;                 // staging LDS dest base (elems)

    // ---- hoisted fragment LDS offsets (tile-invariant) ----
    int aoff[4][2], boff[4][2];
#pragma unroll
    for (int m = 0; m < 4; ++m) {
        int row = wr * 64 + m * 16 + (lane & 15);
        int sw = (row & 7) << 3;
#pragma unroll
        for (int h = 0; h < 2; ++h)
            aoff[m][h] = row * R3BK + ((h * 32 + (lane >> 4) * 8) ^ sw);
    }
#pragma unroll
    for (int nb = 0; nb < 4; ++nb) {
        int row = wc * 64 + nb * 16 + (lane & 15);
        int sw = (row & 7) << 3;
#pragma unroll
        for (int h = 0; h < 2; ++h)
            boff[nb][h] = row * R3BK + ((h * 32 + (lane >> 4) * 8) ^ sw);
    }

    // ---- persistent per-thread staging base pointers (tap/kk via uniform
    //      offsets added at issue time) ----
    const ushort_t* pa[4];
    const ushort_t* pb[2];
#pragma unroll
    for (int s = 0; s < 4; ++s) {
        int r = sr + s * 64;
        int ks = klds ^ ((r & 7) << 3);            // T2 pre-swizzled source col
        if (XMODE == 1) {
            int li = (i0 & (N_ - 1)) + r;          // row within image
            int pr = (li >> 5) * 34 + (li & 31) + 35;   // padded position, tap 0,0
            pa[s] = Ab + ((size_t)(i0 >> 10) * NPAD + pr) * lda + ks;
        } else {
            pa[s] = Ab + (size_t)b * strideA + (size_t)(i0 + r) * lda + ks;
        }
    }
#pragma unroll
    for (int s = 0; s < 2; ++s) {
        int r = sr + s * 64;
        int ks = klds ^ ((r & 7) << 3);
        pb[s] = Bb + (size_t)b * strideB + (size_t)(j0 + r) * ldb + ks;
    }

    int s_tap = 0, s_kk = 0;               // staging-side (tap,kk), tap-minor
    auto STAGE = [&](int slot) {
        long long uA, uB;
        if (XMODE == 1) {
            int dh = s_tap / 3 - 1, dw = s_tap - (s_tap / 3) * 3 - 1;
            uA = (long long)(dh * 34 + dw) * lda + s_kk * R3BK;
        } else {
            uA = (long long)s_tap * tapA + (long long)s_kk * R3BK;
        }
        uB = (long long)s_tap * tapB + (long long)s_kk * R3BK;
#pragma unroll
        for (int s = 0; s < 4; ++s)
            gload16(pa[s] + uA, &As[slot][sbase + s * 4096]);
#pragma unroll
        for (int s = 0; s < 2; ++s)
            gload16(pb[s] + uB, &Bs[slot][sbase + s * 4096]);
        if (++s_tap == ntaps) { s_tap = 0; ++s_kk; }
    };

    // prologue: stage tiles 0,1
    STAGE(0);
    STAGE(1);

    for (int t = 0; t < nt; ++t) {
        int slot = t - (t / 3) * 3;        // t % 3
        if (t + 1 < nt) asm volatile("s_waitcnt vmcnt(6)" ::: "memory");
        else            asm volatile("s_waitcnt vmcnt(0)" ::: "memory");
        __builtin_amdgcn_s_barrier();
        __builtin_amdgcn_sched_barrier(0);

        const short* Aslot = &As[slot][0];
        const short* Bslot = &Bs[slot][0];
        bf16x8 af[4][2], bfr[4][2];
#pragma unroll
        for (int h = 0; h < 2; ++h) {      // h0 reads first (lgkmcnt(8) split)
#pragma unroll
            for (int m = 0; m < 4; ++m)
                af[m][h] = *(const bf16x8*)&Aslot[aoff[m][h]];
#pragma unroll
            for (int nb = 0; nb < 4; ++nb)
                bfr[nb][h] = *(const bf16x8*)&Bslot[boff[nb][h]];
        }

        if (t + 2 < nt) STAGE((t + 2) - ((t + 2) / 3) * 3);

        asm volatile("s_waitcnt lgkmcnt(8)" ::: "memory");
        __builtin_amdgcn_sched_barrier(0);
        __builtin_amdgcn_s_setprio(1);
#pragma unroll
        for (int m = 0; m < 4; ++m)
#pragma unroll
            for (int nb = 0; nb < 4; ++nb)
                acc[m][nb] = __builtin_amdgcn_mfma_f32_16x16x32_bf16(af[m][0], bfr[nb][0], acc[m][nb], 0, 0, 0);
        asm volatile("s_waitcnt lgkmcnt(0)" ::: "memory");
        __builtin_amdgcn_sched_barrier(0);
#pragma unroll
        for (int m = 0; m < 4; ++m)
#pragma unroll
            for (int nb = 0; nb < 4; ++nb)
                acc[m][nb] = __builtin_amdgcn_mfma_f32_16x16x32_bf16(af[m][1], bfr[nb][1], acc[m][nb], 0, 0, 0);
        __builtin_amdgcn_s_setprio(0);
    }

    float scale = SCALE ? *scaleptr : 1.0f;
#pragma unroll
    for (int m = 0; m < 4; ++m) {
#pragma unroll
        for (int nb = 0; nb < 4; ++nb) {
            int i = i0 + wr * 64 + m * 16 + (lane >> 4) * 4;
            int j = j0 + wc * 64 + nb * 16 + (lane & 15);
#pragma unroll
            for (int r = 0; r < 4; ++r) {
                float v = acc[m][nb][r];
                if (BIASMODE == 1) v += bias[i + r];
                if (BIASMODE == 2) v += bias[j];
                if (SCALE) v *= scale;
                if (OUTF32)
                    ((float*)Cb)[(size_t)b * strideC + (size_t)(i + r) * ldc + j] = v;
                else
                    ((ushort_t*)Cb)[(size_t)b * strideC + (size_t)(i + r) * ldc + j] = f2bf(v);
            }
        }
    }
}

// ---------------------------------------------------------------------------
// Workspace layout (bytes). Wall+Xb+catP alias the M region (all dead before
// the M GEMM writes it): 14.2 + 16.8 + 18.9 = 49.9 MB < 67.1 MB.
// ---------------------------------------------------------------------------
constexpr size_t OFF_ZP   = 0;
constexpr size_t OFF_BALL = 1024;
constexpr size_t OFF_WFB  = OFF_BALL + 6144;
constexpr size_t OFF_CAT  = OFF_WFB + (size_t)C_ * C3 * 2;
constexpr size_t OFF_Y    = OFF_CAT + (size_t)B_ * N_ * C3 * 2;
constexpr size_t OFF_DB   = OFF_Y + (size_t)B_ * N_ * C3 * 2;
constexpr size_t OFF_SR   = OFF_DB + (size_t)B_ * C_ * N_ * 2;
constexpr size_t OFF_SST  = OFF_SR + (size_t)B_ * C_ * C_ * 4;
constexpr size_t OFF_MX   = OFF_SST + (size_t)B_ * C_ * C_ * 2;
constexpr size_t OFF_RZ   = OFF_MX + (size_t)B_ * C_ * 4;
constexpr size_t OFF_U    = OFF_RZ + (size_t)B_ * C_ * 4;
constexpr size_t WALL_SZ  = (size_t)9 * C3 * C_ * 2;
constexpr size_t XB_SZ    = (size_t)B_ * C_ * N_ * 2;
constexpr size_t CATP_SZ  = (size_t)B_ * NPAD * C_ * 2;
constexpr size_t OFF_WALL = OFF_U;
constexpr size_t OFF_XB   = OFF_U + WALL_SZ;
constexpr size_t OFF_CATP = OFF_XB + XB_SZ;
constexpr size_t OFF_M    = OFF_U;
constexpr size_t EXT_A    = OFF_CATP + CATP_SZ;
constexpr size_t EXT_B    = OFF_M + (size_t)B_ * N_ * N_ * 4;
constexpr size_t WS_NEED  = EXT_A > EXT_B ? EXT_A : EXT_B;

extern "C" void kernel_launch(void* const* d_in, const int* in_sizes, int n_in,
                              void* d_out, int out_size, void* d_ws, size_t ws_size,
                              hipStream_t stream) {
    const float* x   = (const float*)d_in[0];
    const float* w1  = (const float*)d_in[1];
    const float* b1  = (const float*)d_in[2];
    const float* w2  = (const float*)d_in[3];
    const float* b2  = (const float*)d_in[4];
    const float* w3  = (const float*)d_in[5];
    const float* b3  = (const float*)d_in[6];
    const float* alpha = (const float*)d_in[7];
    const float* beta  = (const float*)d_in[8];
    const float* wf  = (const float*)d_in[9];
    const float* bfv = (const float*)d_in[10];
    float* out = (float*)d_out;
    char* ws = (char*)d_ws;
    if (ws_size < WS_NEED) return;

    ushort_t* zp   = (ushort_t*)(ws + OFF_ZP);
    float*    ball = (float*)(ws + OFF_BALL);
    ushort_t* Wfb  = (ushort_t*)(ws + OFF_WFB);
    ushort_t* cat  = (ushort_t*)(ws + OFF_CAT);
    ushort_t* Y    = (ushort_t*)(ws + OFF_Y);
    ushort_t* Db   = (ushort_t*)(ws + OFF_DB);
    float*    Sr   = (float*)(ws + OFF_SR);
    ushort_t* Sst  = (ushort_t*)(ws + OFF_SST);
    float*    mxv  = (float*)(ws + OFF_MX);
    float*    rzv  = (float*)(ws + OFF_RZ);
    ushort_t* Wall = (ushort_t*)(ws + OFF_WALL);
    ushort_t* Xb   = (ushort_t*)(ws + OFF_XB);
    ushort_t* catP = (ushort_t*)(ws + OFF_CATP);
    float*    Mb   = (float*)(ws + OFF_M);

    // zero the catP pad ring (interior overwritten by castx)
    hipMemsetAsync(catP, 0, CATP_SZ, stream);

    castwf_kernel<<<(C_ * C3) / 256, 256, 0, stream>>>(wf, Wfb, zp, b1, b2, b3, ball);
    castw3_kernel<<<(3 * 9 * C_ * C_) / 256, 256, 0, stream>>>(w1, w2, w3, Wall);
    castx_kernel<<<dim3(N_ / 32, C_ / 32, B_), 256, 0, stream>>>(x, Xb, cat, catP);

    // Fused 3-conv, ONE dispatch: Y[(b,n)][co_all] over Wall[t][1536][512].
    // 12 x 64 = 768 blocks; catP addressing + kk-major keeps re-reads L2-hot.
    gemm_r3_kernel<1, 0, 2, 0><<<dim3(12, 64, 1), 512, 0, stream>>>(
        catP, C_, 0, 0,
        Wall, C_, 0, (long long)C3 * C_,
        Y, C3, 0,
        C_, 9, ball, nullptr, zp);
    // Db[b][co][n] = transpose of Y[:, 1024:1536]
    transp_kernel<<<dim3(N_ / 32, C_ / 32, B_), 256, 0, stream>>>(Y, Db);
    // Sraw[c][d] = Xb . Xb^T (fp32)  (128x128 2-phase baseline kernel)
    gemm_bt_kernel<0, 1, 0, 0, 0><<<dim3(4, 4, B_), 256, 0, stream>>>(
        Xb, N_, (long long)C_ * N_, 0,
        Xb, N_, (long long)C_ * N_, 0,
        Sr, C_, (long long)C_ * C_,
        N_, 1, nullptr, nullptr, zp);
    rowstats_kernel<<<dim3(C_, B_), 256, 0, stream>>>(Sr, mxv, rzv);
    sst_kernel<<<(B_ * C_ * C_ / 4) / 256, 256, 0, stream>>>(Sr, mxv, rzv, Sst);
    // M[n][m] = At . Bt^T (fp32), At = Y[:, :512], Bt = Y[:, 512:1024]
    gemm_r3_kernel<0, 1, 0, 0><<<dim3(8, 4, B_), 512, 0, stream>>>(
        Y, C3, (long long)N_ * C3, 0,
        Y + 512, C3, (long long)N_ * C3, 0,
        Mb, N_, (long long)N_ * N_,
        C_, 1, nullptr, nullptr, zp);
    // row softmax -> bf16 P in place (row stride 2048 ushorts)
    softmax_kernel<<<dim3(N_, B_), 256, 0, stream>>>(Mb);
    // spat_t[n][c] = alpha * P . Db^T  -> cat cols [512,1024)
    gemm_r3_kernel<0, 0, 0, 1><<<dim3(4, 4, B_), 512, 0, stream>>>(
        (const ushort_t*)Mb, 2048, (long long)N_ * 2048, 0,
        Db, N_, (long long)C_ * N_, 0,
        cat + 512, C3, (long long)N_ * C3,
        N_, 1, nullptr, alpha, zp);
    // chan_t[n][c] = beta * Xt . Sst^T -> cat cols [1024,1536)
    gemm_r3_kernel<0, 0, 0, 1><<<dim3(4, 4, B_), 512, 0, stream>>>(
        cat, C3, (long long)N_ * C3, 0,
        Sst, C_, (long long)C_ * C_, 0,
        cat + 1024, C3, (long long)N_ * C3,
        C_, 1, nullptr, beta, zp);
    // out[co][n] = Wfb . cat^T + bf (fp32)
    gemm_r3_kernel<0, 1, 1, 0><<<dim3(8, 2, B_), 512, 0, stream>>>(
        Wfb, C3, 0, 0,
        cat, C3, (long long)N_ * C3, 0,
        out, N_, (long long)C_ * N_,
        C3, 1, bfv, nullptr, zp);
}